// Round 7
// baseline (189.781 us; speedup 1.0000x reference)
//
#include <hip/hip_runtime.h>
#include <hip/hip_bf16.h>

// Problem constants (from reference)
#define NW   8192
#define NS   8192
#define FD   1024
#define EMB  128
#define QN   1024
#define NC   80

typedef unsigned short ushort_t;
typedef unsigned int   uint_t;
typedef __attribute__((ext_vector_type(8))) short short8;
typedef __attribute__((ext_vector_type(4))) float f32x4;

// ---------- workspace layout (element offsets, 4B units) ----------
#define OFF_Q      0u           // float [NW*EMB]
#define OFF_K      1048576u     // float [NS*EMB]
#define OFF_TABLE  2097152u     // int   [NC*8192] — aliases Wt (enc runs before ranktab)
#define OFF_WTQ    2097152u     // ushort[1024*128] (aliases table)
#define OFF_WTK    2129920u     // ushort[1024*128]
#define OFF_HIST   2752512u     // int   [128]
#define OFF_RANK   2752640u     // int   [NW]
#define OFF_CNT    2760832u     // int   [1] completion counter
#define OFF_BHS    2785408u     // int   [32*NC]
#define OFF_BHW    2787968u     // int   [32*NC]
#define OFF_ACC    2790528u     // float [2] : {sum_ce, valid_count}
#define OFF_QT     2790532u     // ushort[1024*128] (Qt: queue^T bf16)

__device__ __forceinline__ ushort_t f2bf(float f) {   // fp32 -> bf16 RNE
    uint_t u = __float_as_uint(f);
    u = (u + 0x7fffu + ((u >> 16) & 1u)) >> 16;
    return (ushort_t)u;
}
__device__ __forceinline__ uint_t pack2(float a, float b) {
    return (uint_t)f2bf(a) | ((uint_t)f2bf(b) << 16);
}

// ============ K1: fused convert/transpose + per-block label histograms + init ============
// blocks [0,384): cvt — z=bx>>7: 0 Wq->Wtq, 1 Wk->Wtk (tiled [kb][n][kk]), 2 queue->Qt [n][k]
// blocks [384,448): bh — per-256-chunk class histograms for s (z=0) and w (z=1)
__global__ __launch_bounds__(256) void cvtbh_k(const float* __restrict__ Wq,
                                               const float* __restrict__ Wk,
                                               const float* __restrict__ queue,
                                               const int* __restrict__ s_lab,
                                               const int* __restrict__ w_lab,
                                               ushort_t* __restrict__ Wtq,
                                               ushort_t* __restrict__ Wtk,
                                               ushort_t* __restrict__ Qt,
                                               int* __restrict__ bhs,
                                               int* __restrict__ bhw,
                                               float* __restrict__ accum,
                                               int* __restrict__ counter) {
    int bx = blockIdx.x;
    int t = threadIdx.x;
    if (bx >= 384) {   // ---- bh part ----
        __shared__ int h[NC];
        int b2 = bx - 384, z = b2 >> 5, cb = b2 & 31;
        const int* lab = z ? w_lab : s_lab;
        int* bh = z ? bhw : bhs;
        if (t < NC) h[t] = 0;
        __syncthreads();
        atomicAdd(&h[lab[cb * 256 + t]], 1);
        __syncthreads();
        if (t < NC) bh[cb * NC + t] = h[t];
        return;
    }
    // ---- cvt part ----
    __shared__ float tile[32][33];
    int z = bx >> 7, flat = bx & 127;
    if (z == 0 && flat == 0) {
        if (t < 2) accum[t] = 0.0f;
        if (t == 2) *counter = 0;
    }
    const float* in; ushort_t* out; int r0, c0, C;
    if (z < 2) { in = z ? Wk : Wq; out = z ? Wtk : Wtq; C = 128;
                 r0 = (flat >> 2) * 32; c0 = (flat & 3) * 32; }
    else       { in = queue; out = Qt; C = 1024;
                 r0 = (flat & 3) * 32; c0 = (flat >> 2) * 32; }
    int i = t >> 3, j0 = (t & 7) * 4;
    float4 v = *(const float4*)(in + (size_t)(r0 + i) * C + c0 + j0);
    tile[i][j0] = v.x; tile[i][j0 + 1] = v.y; tile[i][j0 + 2] = v.z; tile[i][j0 + 3] = v.w;
    __syncthreads();
    uint2 pk;
    pk.x = pack2(tile[j0][i], tile[j0 + 1][i]);
    pk.y = pack2(tile[j0 + 2][i], tile[j0 + 3][i]);
    size_t oaddr;
    if (z < 2) oaddr = ((size_t)(r0 >> 5) * 128 + (c0 + i)) * 32 + j0;   // tiled [kb][n][kk]
    else       oaddr = (size_t)(c0 + i) * 128 + (r0 + j0);               // plain [n][k]
    *(uint2*)(out + oaddr) = pk;
}

// ============ K2: encoder GEMM (MFMA, zero-LDS, 3-deep register prefetch) ============
// grid 1024: bx>>9 = encoder, bx&511 = 16-row tile. 4 waves N-split: wave wv -> cols wv*32..+31.
// 16 waves/CU; 4 named prefetch sets, issue-to-use distance = 3 compute periods.
__global__ __launch_bounds__(256) void enc_mfma_k(const float* __restrict__ A0,
                                                  const float* __restrict__ A1,
                                                  const ushort_t* __restrict__ Wt0,
                                                  const ushort_t* __restrict__ Wt1,
                                                  const float* __restrict__ b0_,
                                                  const float* __restrict__ b1_,
                                                  float* __restrict__ out0,
                                                  float* __restrict__ out1) {
    int bx = blockIdx.x;
    int which = bx >> 9;
    int mtile = bx & 511;
    const float*    A    = which ? A1 : A0;
    const ushort_t* Wt   = which ? Wt1 : Wt0;
    const float*    bias = which ? b1_ : b0_;
    float*          out  = which ? out1 : out0;

    int t = threadIdx.x;
    int wv = t >> 6, ln = t & 63;
    int lane15 = ln & 15, kg = ln >> 4;
    int row0 = mtile * 16;
    int n0 = wv * 32;

    const float* arow = A + (size_t)(row0 + lane15) * FD + kg * 8;
    const ushort_t* wbase = Wt + (n0 + lane15) * 32 + kg * 8;

    f32x4 acc0 = (f32x4){0.f, 0.f, 0.f, 0.f};
    f32x4 acc1 = (f32x4){0.f, 0.f, 0.f, 0.f};

    // 4 named prefetch sets (never runtime-indexed)
    float4 a0l, a0h, a1l, a1h, a2l, a2h, a3l, a3h;
    uint4  p00, p01, p10, p11, p20, p21, p30, p31;

#define LD_SET(al, ah, q0, q1, KB)                                            \
    { const float* ap = arow + (KB) * 32;                                     \
      al = *(const float4*)ap; ah = *(const float4*)(ap + 4);                 \
      const ushort_t* wp = wbase + (size_t)(KB) * 4096;                       \
      q0 = *(const uint4*)wp; q1 = *(const uint4*)(wp + 512); }

#define MFMA_SET(al, ah, q0, q1)                                              \
    { uint4 pk;                                                               \
      pk.x = pack2(al.x, al.y); pk.y = pack2(al.z, al.w);                     \
      pk.z = pack2(ah.x, ah.y); pk.w = pack2(ah.z, ah.w);                     \
      short8 af = __builtin_bit_cast(short8, pk);                             \
      acc0 = __builtin_amdgcn_mfma_f32_16x16x32_bf16(                         \
          af, __builtin_bit_cast(short8, q0), acc0, 0, 0, 0);                 \
      acc1 = __builtin_amdgcn_mfma_f32_16x16x32_bf16(                         \
          af, __builtin_bit_cast(short8, q1), acc1, 0, 0, 0); }

    LD_SET(a0l, a0h, p00, p01, 0)
    LD_SET(a1l, a1h, p10, p11, 1)
    LD_SET(a2l, a2h, p20, p21, 2)

#pragma unroll 1
    for (int kb = 0; kb < 32; kb += 4) {
        LD_SET(a3l, a3h, p30, p31, kb + 3)
        MFMA_SET(a0l, a0h, p00, p01)
        if (kb < 28) LD_SET(a0l, a0h, p00, p01, kb + 4)
        MFMA_SET(a1l, a1h, p10, p11)
        if (kb < 28) LD_SET(a1l, a1h, p10, p11, kb + 5)
        MFMA_SET(a2l, a2h, p20, p21)
        if (kb < 28) LD_SET(a2l, a2h, p20, p21, kb + 6)
        MFMA_SET(a3l, a3h, p30, p31)
    }
#undef LD_SET
#undef MFMA_SET

    // epilogue: C[row][col], row-within-16 = kg*4+j, col = n0 + nt*16 + lane15
    {
        int col0 = n0 + lane15, col1 = n0 + 16 + lane15;
        float bv0 = bias[col0], bv1 = bias[col1];
        int rbase = row0 + kg * 4;
#pragma unroll
        for (int j = 0; j < 4; j++) {
            out[(size_t)(rbase + j) * EMB + col0] = acc0[j] + bv0;
            out[(size_t)(rbase + j) * EMB + col1] = acc1[j] + bv1;
        }
    }
}

// ============ K3: rank/occ + direct table write (+hist) ============
// grid 64: bx>>5 = array (0=s: write table[c][occ]=j ; 1=w: write rank[j]). Block 0 sums hist.
__global__ __launch_bounds__(256) void ranktab_k(const int* __restrict__ s, const int* __restrict__ w,
                                                 const int* __restrict__ bhs, const int* __restrict__ bhw,
                                                 int* __restrict__ table, int* __restrict__ rank,
                                                 int* __restrict__ hist) {
    __shared__ int ll[256];
    int bx = blockIdx.x, z = bx >> 5, cb = bx & 31;
    const int* lab = z ? w : s;
    const int* bh = z ? bhw : bhs;
    int t = threadIdx.x;
    int j = cb * 256 + t;
    int c = lab[j];
    ll[t] = c;
    __syncthreads();
    int r = 0;
    for (int b = 0; b < cb; b++) r += bh[b * NC + c];
    for (int jj = 0; jj < t; jj++) r += (ll[jj] == c) ? 1 : 0;
    if (z) rank[j] = r;
    else   table[c * 8192 + r] = j;
    if (bx == 0 && t < 128) {
        int h = 0;
        if (t < NC)
            for (int b = 0; b < 32; b++) h += bhs[b * NC + t];
        hist[t] = h;
    }
}

// ============ K4: fused idx + lpos + l_neg (MFMA) + online-softmax CE + last-block final ====
// grid 256 x 256 thr: 32 q-rows/block; waves 2x2 (wm=row half, wn=col half of 128-col chunk).
__global__ __launch_bounds__(256) void ce_mfma_k(const float* __restrict__ q,
                                                 const float* __restrict__ k,
                                                 const ushort_t* __restrict__ Qt,
                                                 const int* __restrict__ rank,
                                                 const int* __restrict__ table,
                                                 const int* __restrict__ w,
                                                 const int* __restrict__ hist,
                                                 float* __restrict__ accum,
                                                 int* __restrict__ counter,
                                                 float* __restrict__ outp) {
    __shared__ int   idx_lds[32];
    __shared__ float lpos_lds[32];
    __shared__ float mg[2][32][2];
    int t = threadIdx.x;
    int r0 = blockIdx.x * 32;

    // inline idx: idx[i] = table[w[i]][rank[i] % cnt]
    if (t < 32) {
        int i = r0 + t;
        int c = w[i];
        int cc = hist[c];
        idx_lds[t] = (cc > 0) ? table[c * 8192 + (rank[i] % cc)] : 0;
    }
    __syncthreads();

    // fused l_pos: row r0+(t>>3), 8 threads x 16 floats each (fp32 exact)
    {
        int rr = t >> 3;
        int o = (t & 7) * 16;
        const float4* qa = (const float4*)(q + (size_t)(r0 + rr) * EMB + o);
        const float4* ka = (const float4*)(k + (size_t)idx_lds[rr] * EMB + o);
        float s = 0.f;
#pragma unroll
        for (int p = 0; p < 4; p++) {
            float4 a = qa[p], b = ka[p];
            s += a.x * b.x + a.y * b.y + a.z * b.z + a.w * b.w;
        }
        s += __shfl_xor(s, 1); s += __shfl_xor(s, 2); s += __shfl_xor(s, 4);
        if ((t & 7) == 0) lpos_lds[rr] = s;
    }

    int wv = t >> 6, ln = t & 63;
    int wm = wv >> 1, wn = wv & 1;
    int lane15 = ln & 15, kg = ln >> 4;

    // A-frags direct from q global (each row read by 2 waves)
    short8 afr[4];
#pragma unroll
    for (int ks = 0; ks < 4; ks++) {
        const float4* p = (const float4*)(q + (size_t)(r0 + wm * 16 + lane15) * EMB + ks * 32 + kg * 8);
        float4 a = p[0], b = p[1];
        uint4 pk;
        pk.x = pack2(a.x, a.y); pk.y = pack2(a.z, a.w);
        pk.z = pack2(b.x, b.y); pk.w = pack2(b.z, b.w);
        afr[ks] = __builtin_bit_cast(short8, pk);
    }

    float run_m[4], run_l[4];
#pragma unroll
    for (int j = 0; j < 4; j++) { run_m[j] = -1e30f; run_l[j] = 0.f; }

#pragma unroll 1
    for (int nc = 0; nc < 8; nc++) {
        f32x4 acc[4];
#pragma unroll
        for (int nt = 0; nt < 4; nt++) acc[nt] = (f32x4){0.f, 0.f, 0.f, 0.f};
#pragma unroll
        for (int nt = 0; nt < 4; nt++) {
            size_t nrow = (size_t)(nc * 128 + wn * 64 + nt * 16 + lane15) * 128 + kg * 8;
#pragma unroll
            for (int ks = 0; ks < 4; ks++) {
                short8 bf = __builtin_bit_cast(short8, *(const uint4*)(Qt + nrow + ks * 32));
                acc[nt] = __builtin_amdgcn_mfma_f32_16x16x32_bf16(afr[ks], bf, acc[nt], 0, 0, 0);
            }
        }
        // online softmax; lane's rows = wm*16 + kg*4+j
#pragma unroll
        for (int j = 0; j < 4; j++) {
            float v0 = acc[0][j], v1 = acc[1][j], v2 = acc[2][j], v3 = acc[3][j];
            float mc = fmaxf(fmaxf(v0, v1), fmaxf(v2, v3));
            mc = fmaxf(mc, __shfl_xor(mc, 1));
            mc = fmaxf(mc, __shfl_xor(mc, 2));
            mc = fmaxf(mc, __shfl_xor(mc, 4));
            mc = fmaxf(mc, __shfl_xor(mc, 8));
            float nm = fmaxf(run_m[j], mc);
            float s = __expf(v0 - nm) + __expf(v1 - nm) + __expf(v2 - nm) + __expf(v3 - nm);
            s += __shfl_xor(s, 1);
            s += __shfl_xor(s, 2);
            s += __shfl_xor(s, 4);
            s += __shfl_xor(s, 8);
            run_l[j] = run_l[j] * __expf(run_m[j] - nm) + s;
            run_m[j] = nm;
        }
    }

    if (lane15 == 0) {
#pragma unroll
        for (int j = 0; j < 4; j++) {
            int rl = wm * 16 + kg * 4 + j;
            mg[wn][rl][0] = run_m[j];
            mg[wn][rl][1] = run_l[j];
        }
    }
    __syncthreads();
    if (wv == 0) {
        float cv = 0.f, cc = 0.f;
        if (t < 32) {
            int i = r0 + t;
            float m0 = mg[0][t][0], l0 = mg[0][t][1];
            float m1 = mg[1][t][0], l1 = mg[1][t][1];
            float lp = lpos_lds[t];
            float m = fmaxf(fmaxf(m0, m1), lp);
            float l = l0 * __expf(m0 - m) + l1 * __expf(m1 - m) + __expf(lp - m);
            float ce = -(lp - m - __logf(l));
            if (hist[w[i]] > 0) { cv = ce; cc = 1.f; }
        }
        cv += __shfl_xor(cv, 1);  cc += __shfl_xor(cc, 1);
        cv += __shfl_xor(cv, 2);  cc += __shfl_xor(cc, 2);
        cv += __shfl_xor(cv, 4);  cc += __shfl_xor(cc, 4);
        cv += __shfl_xor(cv, 8);  cc += __shfl_xor(cc, 8);
        cv += __shfl_xor(cv, 16); cc += __shfl_xor(cc, 16);
        cv += __shfl_xor(cv, 32); cc += __shfl_xor(cc, 32);
        if (t == 0) {
            atomicAdd(&accum[0], cv);
            atomicAdd(&accum[1], cc);
            __threadfence();
            int done = atomicAdd(counter, 1);
            if (done == 255) {   // last block finalizes
                float s = atomicAdd(&accum[0], 0.0f);
                float c = atomicAdd(&accum[1], 0.0f);
                outp[0] = s / fmaxf(c, 1.0f);
            }
        }
    }
}

extern "C" void kernel_launch(void* const* d_in, const int* in_sizes, int n_in,
                              void* d_out, int out_size, void* d_ws, size_t ws_size,
                              hipStream_t stream) {
    const float* feats_strong = (const float*)d_in[0];
    const float* feats_weak   = (const float*)d_in[1];
    const int*   s_lab        = (const int*)d_in[2];
    const int*   w_lab        = (const int*)d_in[3];
    const float* Wq           = (const float*)d_in[4];
    const float* bq           = (const float*)d_in[5];
    const float* Wk           = (const float*)d_in[6];
    const float* bk           = (const float*)d_in[7];
    const float* queue        = (const float*)d_in[8];

    float*    wsf = (float*)d_ws;
    int*      wsi = (int*)d_ws;

    float*    q_g   = wsf + OFF_Q;
    float*    k_g   = wsf + OFF_K;
    int*      table = wsi + OFF_TABLE;
    ushort_t* Wtq   = (ushort_t*)(wsi + OFF_WTQ);
    ushort_t* Wtk   = (ushort_t*)(wsi + OFF_WTK);
    int*      hist  = wsi + OFF_HIST;
    int*      rank  = wsi + OFF_RANK;
    int*      cnt   = wsi + OFF_CNT;
    int*      bhs   = wsi + OFF_BHS;
    int*      bhw   = wsi + OFF_BHW;
    float*    accum = wsf + OFF_ACC;
    ushort_t* Qt    = (ushort_t*)(wsi + OFF_QT);

    // K1: bf16 convert/transpose + label block-histograms + zero accum/counter
    cvtbh_k<<<448, 256, 0, stream>>>(Wq, Wk, queue, s_lab, w_lab,
                                     Wtq, Wtk, Qt, bhs, bhw, accum, cnt);
    // K2: both encoder GEMMs (reads Wt region before K3 clobbers it with table)
    enc_mfma_k<<<1024, 256, 0, stream>>>(feats_weak, feats_strong, Wtq, Wtk, bq, bk, q_g, k_g);
    // K3: rank + table + hist
    ranktab_k<<<64, 256, 0, stream>>>(s_lab, w_lab, bhs, bhw, table, rank, hist);
    // K4: idx + lpos + l_neg GEMM + CE + finalize
    ce_mfma_k<<<256, 256, 0, stream>>>(q_g, k_g, Qt, rank, table, w_lab, hist,
                                       accum, cnt, (float*)d_out);
}

// Round 8
// 186.158 us; speedup vs baseline: 1.0195x; 1.0195x over previous
//
#include <hip/hip_runtime.h>
#include <hip/hip_bf16.h>

// Problem constants (from reference)
#define NW   8192
#define NS   8192
#define FD   1024
#define EMB  128
#define QN   1024
#define NC   80

typedef unsigned short ushort_t;
typedef unsigned int   uint_t;
typedef __attribute__((ext_vector_type(8))) short short8;
typedef __attribute__((ext_vector_type(4))) float f32x4;

// ---------- workspace layout (element offsets, 4B units) ----------
#define OFF_Q      0u           // float [NW*EMB]
#define OFF_K      1048576u     // float [NS*EMB]
#define OFF_TABLE  2097152u     // int   [NC*8192] — aliases Wt (enc runs before ranktab)
#define OFF_WTQ    2097152u     // ushort[1024*128] (aliases table)
#define OFF_WTK    2129920u     // ushort[1024*128]
#define OFF_HIST   2752512u     // int   [128]
#define OFF_RANK   2752640u     // int   [NW]
#define OFF_CNT    2760832u     // int   [1] completion counter
#define OFF_BHS    2785408u     // int   [32*NC]
#define OFF_BHW    2787968u     // int   [32*NC]
#define OFF_ACC    2790528u     // float [2] : {sum_ce, valid_count}
#define OFF_QT     2790532u     // ushort[1024*128] (Qt: queue^T bf16)

__device__ __forceinline__ ushort_t f2bf(float f) {   // fp32 -> bf16 RNE
    uint_t u = __float_as_uint(f);
    u = (u + 0x7fffu + ((u >> 16) & 1u)) >> 16;
    return (ushort_t)u;
}
__device__ __forceinline__ uint_t pack2(float a, float b) {
    return (uint_t)f2bf(a) | ((uint_t)f2bf(b) << 16);
}

// ============ K1: fused convert/transpose + per-block label histograms + init ============
__global__ __launch_bounds__(256) void cvtbh_k(const float* __restrict__ Wq,
                                               const float* __restrict__ Wk,
                                               const float* __restrict__ queue,
                                               const int* __restrict__ s_lab,
                                               const int* __restrict__ w_lab,
                                               ushort_t* __restrict__ Wtq,
                                               ushort_t* __restrict__ Wtk,
                                               ushort_t* __restrict__ Qt,
                                               int* __restrict__ bhs,
                                               int* __restrict__ bhw,
                                               float* __restrict__ accum,
                                               int* __restrict__ counter) {
    int bx = blockIdx.x;
    int t = threadIdx.x;
    if (bx >= 384) {   // ---- bh part ----
        __shared__ int h[NC];
        int b2 = bx - 384, z = b2 >> 5, cb = b2 & 31;
        const int* lab = z ? w_lab : s_lab;
        int* bh = z ? bhw : bhs;
        if (t < NC) h[t] = 0;
        __syncthreads();
        atomicAdd(&h[lab[cb * 256 + t]], 1);
        __syncthreads();
        if (t < NC) bh[cb * NC + t] = h[t];
        return;
    }
    // ---- cvt part ----
    __shared__ float tile[32][33];
    int z = bx >> 7, flat = bx & 127;
    if (z == 0 && flat == 0) {
        if (t < 2) accum[t] = 0.0f;
        if (t == 2) *counter = 0;
    }
    const float* in; ushort_t* out; int r0, c0, C;
    if (z < 2) { in = z ? Wk : Wq; out = z ? Wtk : Wtq; C = 128;
                 r0 = (flat >> 2) * 32; c0 = (flat & 3) * 32; }
    else       { in = queue; out = Qt; C = 1024;
                 r0 = (flat & 3) * 32; c0 = (flat >> 2) * 32; }
    int i = t >> 3, j0 = (t & 7) * 4;
    float4 v = *(const float4*)(in + (size_t)(r0 + i) * C + c0 + j0);
    tile[i][j0] = v.x; tile[i][j0 + 1] = v.y; tile[i][j0 + 2] = v.z; tile[i][j0 + 3] = v.w;
    __syncthreads();
    uint2 pk;
    pk.x = pack2(tile[j0][i], tile[j0 + 1][i]);
    pk.y = pack2(tile[j0 + 2][i], tile[j0 + 3][i]);
    size_t oaddr;
    if (z < 2) oaddr = ((size_t)(r0 >> 5) * 128 + (c0 + i)) * 32 + j0;   // tiled [kb][n][kk]
    else       oaddr = (size_t)(c0 + i) * 128 + (r0 + j0);               // plain [n][k]
    *(uint2*)(out + oaddr) = pk;
}

// ============ K2: encoder GEMM (MFMA, zero-LDS, 3-deep register prefetch) ============
// grid 1024: bx>>9 = encoder, bx&511 = 16-row tile. 4 waves N-split: wave wv -> cols wv*32..+31.
// __launch_bounds__(256,4): VGPR cap 128 so all 4 prefetch sets stay in registers
// (round-7 failure: default bounds -> 48 VGPR -> compiler sank loads to uses).
__global__ __launch_bounds__(256, 4) void enc_mfma_k(const float* __restrict__ A0,
                                                     const float* __restrict__ A1,
                                                     const ushort_t* __restrict__ Wt0,
                                                     const ushort_t* __restrict__ Wt1,
                                                     const float* __restrict__ b0_,
                                                     const float* __restrict__ b1_,
                                                     float* __restrict__ out0,
                                                     float* __restrict__ out1) {
    int bx = blockIdx.x;
    int which = bx >> 9;
    int mtile = bx & 511;
    const float*    A    = which ? A1 : A0;
    const ushort_t* Wt   = which ? Wt1 : Wt0;
    const float*    bias = which ? b1_ : b0_;
    float*          out  = which ? out1 : out0;

    int t = threadIdx.x;
    int wv = t >> 6, ln = t & 63;
    int lane15 = ln & 15, kg = ln >> 4;
    int row0 = mtile * 16;
    int n0 = wv * 32;

    const float* arow = A + (size_t)(row0 + lane15) * FD + kg * 8;
    const ushort_t* wbase = Wt + (n0 + lane15) * 32 + kg * 8;

    f32x4 acc0 = (f32x4){0.f, 0.f, 0.f, 0.f};
    f32x4 acc1 = (f32x4){0.f, 0.f, 0.f, 0.f};

    // 4 named prefetch sets (never runtime-indexed)
    float4 a0l, a0h, a1l, a1h, a2l, a2h, a3l, a3h;
    uint4  p00, p01, p10, p11, p20, p21, p30, p31;

#define LD_SET(al, ah, q0, q1, KB)                                            \
    { const float* ap = arow + (KB) * 32;                                     \
      al = *(const float4*)ap; ah = *(const float4*)(ap + 4);                 \
      const ushort_t* wp = wbase + (size_t)(KB) * 4096;                       \
      q0 = *(const uint4*)wp; q1 = *(const uint4*)(wp + 512); }

#define MFMA_SET(al, ah, q0, q1)                                              \
    { uint4 pk;                                                               \
      pk.x = pack2(al.x, al.y); pk.y = pack2(al.z, al.w);                     \
      pk.z = pack2(ah.x, ah.y); pk.w = pack2(ah.z, ah.w);                     \
      short8 af = __builtin_bit_cast(short8, pk);                             \
      acc0 = __builtin_amdgcn_mfma_f32_16x16x32_bf16(                         \
          af, __builtin_bit_cast(short8, q0), acc0, 0, 0, 0);                 \
      acc1 = __builtin_amdgcn_mfma_f32_16x16x32_bf16(                         \
          af, __builtin_bit_cast(short8, q1), acc1, 0, 0, 0); }

    LD_SET(a0l, a0h, p00, p01, 0)
    LD_SET(a1l, a1h, p10, p11, 1)
    LD_SET(a2l, a2h, p20, p21, 2)

#pragma unroll 1
    for (int kb = 0; kb < 32; kb += 4) {
        LD_SET(a3l, a3h, p30, p31, kb + 3)
        MFMA_SET(a0l, a0h, p00, p01)
        if (kb < 28) LD_SET(a0l, a0h, p00, p01, kb + 4)
        MFMA_SET(a1l, a1h, p10, p11)
        if (kb < 28) LD_SET(a1l, a1h, p10, p11, kb + 5)
        MFMA_SET(a2l, a2h, p20, p21)
        if (kb < 28) LD_SET(a2l, a2h, p20, p21, kb + 6)
        MFMA_SET(a3l, a3h, p30, p31)
    }
#undef LD_SET
#undef MFMA_SET

    // epilogue: C[row][col], row-within-16 = kg*4+j, col = n0 + {0,16} + lane15
    {
        int col0 = n0 + lane15, col1 = n0 + 16 + lane15;
        float bv0 = bias[col0], bv1 = bias[col1];
        int rbase = row0 + kg * 4;
#pragma unroll
        for (int j = 0; j < 4; j++) {
            out[(size_t)(rbase + j) * EMB + col0] = acc0[j] + bv0;
            out[(size_t)(rbase + j) * EMB + col1] = acc1[j] + bv1;
        }
    }
}

// ============ K3: rank/occ + direct table write (+hist) ============
__global__ __launch_bounds__(256) void ranktab_k(const int* __restrict__ s, const int* __restrict__ w,
                                                 const int* __restrict__ bhs, const int* __restrict__ bhw,
                                                 int* __restrict__ table, int* __restrict__ rank,
                                                 int* __restrict__ hist) {
    __shared__ int ll[256];
    int bx = blockIdx.x, z = bx >> 5, cb = bx & 31;
    const int* lab = z ? w : s;
    const int* bh = z ? bhw : bhs;
    int t = threadIdx.x;
    int j = cb * 256 + t;
    int c = lab[j];
    ll[t] = c;
    __syncthreads();
    int r = 0;
    for (int b = 0; b < cb; b++) r += bh[b * NC + c];
    for (int jj = 0; jj < t; jj++) r += (ll[jj] == c) ? 1 : 0;
    if (z) rank[j] = r;
    else   table[c * 8192 + r] = j;
    if (bx == 0 && t < 128) {
        int h = 0;
        if (t < NC)
            for (int b = 0; b < 32; b++) h += bhs[b * NC + t];
        hist[t] = h;
    }
}

// ============ K4: fused idx + lpos + l_neg (MFMA) + online-softmax CE + last-block final ====
// grid 512 x 256 thr: 16 q-rows/block; 4 waves = 4 column-quarters (32 cols each) of the
// 128-col chunk; 4-way merge in LDS. 2 blocks/CU.
__global__ __launch_bounds__(256, 4) void ce_mfma_k(const float* __restrict__ q,
                                                    const float* __restrict__ k,
                                                    const ushort_t* __restrict__ Qt,
                                                    const int* __restrict__ rank,
                                                    const int* __restrict__ table,
                                                    const int* __restrict__ w,
                                                    const int* __restrict__ hist,
                                                    float* __restrict__ accum,
                                                    int* __restrict__ counter,
                                                    float* __restrict__ outp) {
    __shared__ int   idx_lds[16];
    __shared__ float lpos_lds[16];
    __shared__ float mg[4][16][2];
    int t = threadIdx.x;
    int r0 = blockIdx.x * 16;

    // inline idx: idx[i] = table[w[i]][rank[i] % cnt]
    if (t < 16) {
        int i = r0 + t;
        int c = w[i];
        int cc = hist[c];
        idx_lds[t] = (cc > 0) ? table[c * 8192 + (rank[i] % cc)] : 0;
    }
    __syncthreads();

    // fused l_pos: row r0+(t>>4), 16 threads x 8 floats each (fp32 exact)
    {
        int rr = t >> 4;
        int o = (t & 15) * 8;
        const float4* qa = (const float4*)(q + (size_t)(r0 + rr) * EMB + o);
        const float4* ka = (const float4*)(k + (size_t)idx_lds[rr] * EMB + o);
        float4 a0 = qa[0], b0 = ka[0], a1 = qa[1], b1 = ka[1];
        float s = a0.x * b0.x + a0.y * b0.y + a0.z * b0.z + a0.w * b0.w
                + a1.x * b1.x + a1.y * b1.y + a1.z * b1.z + a1.w * b1.w;
        s += __shfl_xor(s, 1); s += __shfl_xor(s, 2);
        s += __shfl_xor(s, 4); s += __shfl_xor(s, 8);
        if ((t & 15) == 0) lpos_lds[rr] = s;
    }

    int wv = t >> 6, ln = t & 63;
    int lane15 = ln & 15, kg = ln >> 4;

    // A-frags direct from q global (all waves same 16 rows)
    short8 afr[4];
#pragma unroll
    for (int ks = 0; ks < 4; ks++) {
        const float4* p = (const float4*)(q + (size_t)(r0 + lane15) * EMB + ks * 32 + kg * 8);
        float4 a = p[0], b = p[1];
        uint4 pk;
        pk.x = pack2(a.x, a.y); pk.y = pack2(a.z, a.w);
        pk.z = pack2(b.x, b.y); pk.w = pack2(b.z, b.w);
        afr[ks] = __builtin_bit_cast(short8, pk);
    }

    float run_m[4], run_l[4];
#pragma unroll
    for (int j = 0; j < 4; j++) { run_m[j] = -1e30f; run_l[j] = 0.f; }

#pragma unroll 1
    for (int nc = 0; nc < 8; nc++) {
        f32x4 acc0 = (f32x4){0.f, 0.f, 0.f, 0.f};
        f32x4 acc1 = (f32x4){0.f, 0.f, 0.f, 0.f};
#pragma unroll
        for (int ks = 0; ks < 4; ks++) {
            size_t nrow0 = (size_t)(nc * 128 + wv * 32 + lane15) * 128 + kg * 8;
            short8 bf0 = __builtin_bit_cast(short8, *(const uint4*)(Qt + nrow0 + ks * 32));
            short8 bf1 = __builtin_bit_cast(short8, *(const uint4*)(Qt + nrow0 + 16 * 128 + ks * 32));
            acc0 = __builtin_amdgcn_mfma_f32_16x16x32_bf16(afr[ks], bf0, acc0, 0, 0, 0);
            acc1 = __builtin_amdgcn_mfma_f32_16x16x32_bf16(afr[ks], bf1, acc1, 0, 0, 0);
        }
        // online softmax; lane's rows = kg*4+j
#pragma unroll
        for (int j = 0; j < 4; j++) {
            float v0 = acc0[j], v1 = acc1[j];
            float mc = fmaxf(v0, v1);
            mc = fmaxf(mc, __shfl_xor(mc, 1));
            mc = fmaxf(mc, __shfl_xor(mc, 2));
            mc = fmaxf(mc, __shfl_xor(mc, 4));
            mc = fmaxf(mc, __shfl_xor(mc, 8));
            float nm = fmaxf(run_m[j], mc);
            float s = __expf(v0 - nm) + __expf(v1 - nm);
            s += __shfl_xor(s, 1);
            s += __shfl_xor(s, 2);
            s += __shfl_xor(s, 4);
            s += __shfl_xor(s, 8);
            run_l[j] = run_l[j] * __expf(run_m[j] - nm) + s;
            run_m[j] = nm;
        }
    }

    if (lane15 == 0) {
#pragma unroll
        for (int j = 0; j < 4; j++) {
            int rl = kg * 4 + j;
            mg[wv][rl][0] = run_m[j];
            mg[wv][rl][1] = run_l[j];
        }
    }
    __syncthreads();
    if (wv == 0) {
        float cv = 0.f, cc = 0.f;
        if (t < 16) {
            int i = r0 + t;
            float m0 = mg[0][t][0], l0 = mg[0][t][1];
            float m1 = mg[1][t][0], l1 = mg[1][t][1];
            float m2 = mg[2][t][0], l2 = mg[2][t][1];
            float m3 = mg[3][t][0], l3 = mg[3][t][1];
            float lp = lpos_lds[t];
            float m = fmaxf(fmaxf(fmaxf(m0, m1), fmaxf(m2, m3)), lp);
            float l = l0 * __expf(m0 - m) + l1 * __expf(m1 - m)
                    + l2 * __expf(m2 - m) + l3 * __expf(m3 - m) + __expf(lp - m);
            float ce = -(lp - m - __logf(l));
            if (hist[w[i]] > 0) { cv = ce; cc = 1.f; }
        }
        cv += __shfl_xor(cv, 1);  cc += __shfl_xor(cc, 1);
        cv += __shfl_xor(cv, 2);  cc += __shfl_xor(cc, 2);
        cv += __shfl_xor(cv, 4);  cc += __shfl_xor(cc, 4);
        cv += __shfl_xor(cv, 8);  cc += __shfl_xor(cc, 8);
        if (t == 0) {
            atomicAdd(&accum[0], cv);
            atomicAdd(&accum[1], cc);
            __threadfence();
            int done = atomicAdd(counter, 1);
            if (done == 511) {   // last block finalizes
                float s = atomicAdd(&accum[0], 0.0f);
                float c = atomicAdd(&accum[1], 0.0f);
                outp[0] = s / fmaxf(c, 1.0f);
            }
        }
    }
}

extern "C" void kernel_launch(void* const* d_in, const int* in_sizes, int n_in,
                              void* d_out, int out_size, void* d_ws, size_t ws_size,
                              hipStream_t stream) {
    const float* feats_strong = (const float*)d_in[0];
    const float* feats_weak   = (const float*)d_in[1];
    const int*   s_lab        = (const int*)d_in[2];
    const int*   w_lab        = (const int*)d_in[3];
    const float* Wq           = (const float*)d_in[4];
    const float* bq           = (const float*)d_in[5];
    const float* Wk           = (const float*)d_in[6];
    const float* bk           = (const float*)d_in[7];
    const float* queue        = (const float*)d_in[8];

    float*    wsf = (float*)d_ws;
    int*      wsi = (int*)d_ws;

    float*    q_g   = wsf + OFF_Q;
    float*    k_g   = wsf + OFF_K;
    int*      table = wsi + OFF_TABLE;
    ushort_t* Wtq   = (ushort_t*)(wsi + OFF_WTQ);
    ushort_t* Wtk   = (ushort_t*)(wsi + OFF_WTK);
    int*      hist  = wsi + OFF_HIST;
    int*      rank  = wsi + OFF_RANK;
    int*      cnt   = wsi + OFF_CNT;
    int*      bhs   = wsi + OFF_BHS;
    int*      bhw   = wsi + OFF_BHW;
    float*    accum = wsf + OFF_ACC;
    ushort_t* Qt    = (ushort_t*)(wsi + OFF_QT);

    // K1: bf16 convert/transpose + label block-histograms + zero accum/counter
    cvtbh_k<<<448, 256, 0, stream>>>(Wq, Wk, queue, s_lab, w_lab,
                                     Wtq, Wtk, Qt, bhs, bhw, accum, cnt);
    // K2: both encoder GEMMs (reads Wt region before K3 clobbers it with table)
    enc_mfma_k<<<1024, 256, 0, stream>>>(feats_weak, feats_strong, Wtq, Wtk, bq, bk, q_g, k_g);
    // K3: rank + table + hist
    ranktab_k<<<64, 256, 0, stream>>>(s_lab, w_lab, bhs, bhw, table, rank, hist);
    // K4: idx + lpos + l_neg GEMM + CE + finalize
    ce_mfma_k<<<512, 256, 0, stream>>>(q_g, k_g, Qt, rank, table, w_lab, hist,
                                       accum, cnt, (float*)d_out);
}

// Round 9
// 185.213 us; speedup vs baseline: 1.0247x; 1.0051x over previous
//
#include <hip/hip_runtime.h>
#include <hip/hip_bf16.h>

// Problem constants (from reference)
#define NW   8192
#define NS   8192
#define FD   1024
#define EMB  128
#define QN   1024
#define NC   80

typedef unsigned short ushort_t;
typedef unsigned int   uint_t;
typedef __attribute__((ext_vector_type(8))) short short8;
typedef __attribute__((ext_vector_type(4))) float f32x4;

// ---------- workspace layout (element offsets, 4B units) ----------
#define OFF_Q      0u           // float [NW*EMB]
#define OFF_K      1048576u     // float [NS*EMB]
#define OFF_TABLE  2097152u     // int   [NC*8192] — aliases Wt (enc runs before ranktab)
#define OFF_WTQ    2097152u     // ushort[1024*128] (aliases table)
#define OFF_WTK    2129920u     // ushort[1024*128]
#define OFF_HIST   2752512u     // int   [128]
#define OFF_RANK   2752640u     // int   [NW]
#define OFF_CNT    2760832u     // int   [1] completion counter
#define OFF_BHS    2785408u     // int   [32*NC]
#define OFF_BHW    2787968u     // int   [32*NC]
#define OFF_ACC    2790528u     // float [2] : {sum_ce, valid_count}
#define OFF_QT     2790532u     // ushort[1024*128] (Qt: queue^T bf16)

__device__ __forceinline__ ushort_t f2bf(float f) {   // fp32 -> bf16 RNE
    uint_t u = __float_as_uint(f);
    u = (u + 0x7fffu + ((u >> 16) & 1u)) >> 16;
    return (ushort_t)u;
}
__device__ __forceinline__ uint_t pack2(float a, float b) {
    return (uint_t)f2bf(a) | ((uint_t)f2bf(b) << 16);
}

// async global->LDS, 16B per lane; LDS dest = uniform base + lane*16
#define GLOAD_LDS16(gp, lp)                                                     \
    __builtin_amdgcn_global_load_lds(                                           \
        (const __attribute__((address_space(1))) void*)(gp),                    \
        (__attribute__((address_space(3))) void*)(lp), 16, 0, 0)

// ============ K1: fused convert/transpose + per-block label histograms + init ============
__global__ __launch_bounds__(256) void cvtbh_k(const float* __restrict__ Wq,
                                               const float* __restrict__ Wk,
                                               const float* __restrict__ queue,
                                               const int* __restrict__ s_lab,
                                               const int* __restrict__ w_lab,
                                               ushort_t* __restrict__ Wtq,
                                               ushort_t* __restrict__ Wtk,
                                               ushort_t* __restrict__ Qt,
                                               int* __restrict__ bhs,
                                               int* __restrict__ bhw,
                                               float* __restrict__ accum,
                                               int* __restrict__ counter) {
    int bx = blockIdx.x;
    int t = threadIdx.x;
    if (bx >= 384) {   // ---- bh part ----
        __shared__ int h[NC];
        int b2 = bx - 384, z = b2 >> 5, cb = b2 & 31;
        const int* lab = z ? w_lab : s_lab;
        int* bh = z ? bhw : bhs;
        if (t < NC) h[t] = 0;
        __syncthreads();
        atomicAdd(&h[lab[cb * 256 + t]], 1);
        __syncthreads();
        if (t < NC) bh[cb * NC + t] = h[t];
        return;
    }
    // ---- cvt part ----
    __shared__ float tile[32][33];
    int z = bx >> 7, flat = bx & 127;
    if (z == 0 && flat == 0) {
        if (t < 2) accum[t] = 0.0f;
        if (t == 2) *counter = 0;
    }
    const float* in; ushort_t* out; int r0, c0, C;
    if (z < 2) { in = z ? Wk : Wq; out = z ? Wtk : Wtq; C = 128;
                 r0 = (flat >> 2) * 32; c0 = (flat & 3) * 32; }
    else       { in = queue; out = Qt; C = 1024;
                 r0 = (flat & 3) * 32; c0 = (flat >> 2) * 32; }
    int i = t >> 3, j0 = (t & 7) * 4;
    float4 v = *(const float4*)(in + (size_t)(r0 + i) * C + c0 + j0);
    tile[i][j0] = v.x; tile[i][j0 + 1] = v.y; tile[i][j0 + 2] = v.z; tile[i][j0 + 3] = v.w;
    __syncthreads();
    uint2 pk;
    pk.x = pack2(tile[j0][i], tile[j0 + 1][i]);
    pk.y = pack2(tile[j0 + 2][i], tile[j0 + 3][i]);
    size_t oaddr;
    if (z < 2) oaddr = ((size_t)(r0 >> 5) * 128 + (c0 + i)) * 32 + j0;   // tiled [kb][n][kk]
    else       oaddr = (size_t)(c0 + i) * 128 + (r0 + j0);               // plain [n][k]
    *(uint2*)(out + oaddr) = pk;
}

// ============ K2: encoder GEMM — m97 pattern: global_load_lds + LDS dbuf + MFMA ============
// grid 256: bx>>7 = encoder, bx&127 = 64-row tile. 4 waves 2x2 (wm,wn).
// LDS per buf: A 8KB (64 rows x 32k fp32, block-major 16B slots: region[mr]+b*256+r*16)
//              B 8KB (128 n x 32kk bf16, group-major: 8192+G*1024+kg*256+n16*16)
// Layouts chosen so global_load_lds (lane-contiguous, no padding) AND ds_read_b128 are
// bank-even (every bank gets exactly 8 dwords per wave b128 read).
__global__ __launch_bounds__(256) void enc_mfma_k(const float* __restrict__ A0,
                                                  const float* __restrict__ A1,
                                                  const ushort_t* __restrict__ Wt0,
                                                  const ushort_t* __restrict__ Wt1,
                                                  const float* __restrict__ b0_,
                                                  const float* __restrict__ b1_,
                                                  float* __restrict__ out0,
                                                  float* __restrict__ out1) {
    __shared__ __align__(16) char smem[32768];   // 2 x (8KB A + 8KB B)

    int bx = blockIdx.x;
    int which = bx >> 7;
    int mtile = bx & 127;
    const float*    A    = which ? A1 : A0;
    const ushort_t* Wt   = which ? Wt1 : Wt0;
    const float*    bias = which ? b1_ : b0_;
    float*          out  = which ? out1 : out0;
    int row0 = mtile * 64;

    int t = threadIdx.x;
    int wv = t >> 6, ln = t & 63;
    int wm = wv >> 1, wn = wv & 1;
    int lane15 = ln & 15, kg = ln >> 4;
    int lrow = ln & 15;       // staging row-within-16
    int lblk = ln >> 4;       // staging block 0..3

    // per-lane global staging bases (k-invariant parts)
    const float*    gA = A + (size_t)(row0 + wv * 16 + lrow) * FD + lblk * 4;
    const ushort_t* gB0 = Wt + (size_t)(wv * 32 + lrow) * 32 + lblk * 8;       // a=0
    const ushort_t* gB1 = Wt + (size_t)(wv * 32 + 16 + lrow) * 32 + lblk * 8;  // a=1

    f32x4 acc[2][4];
#pragma unroll
    for (int a = 0; a < 2; a++)
#pragma unroll
        for (int b = 0; b < 4; b++) acc[a][b] = (f32x4){0.f, 0.f, 0.f, 0.f};

#define STAGE(BUF, KB)                                                          \
    { char* lb = smem + (BUF) * 16384;                                          \
      GLOAD_LDS16(gA + (size_t)(KB) * 32,          lb + wv * 2048);             \
      GLOAD_LDS16(gA + (size_t)(KB) * 32 + 16,     lb + wv * 2048 + 1024);      \
      GLOAD_LDS16(gB0 + (size_t)(KB) * 4096, lb + 8192 + (wv * 2) * 1024);      \
      GLOAD_LDS16(gB1 + (size_t)(KB) * 4096, lb + 8192 + (wv * 2 + 1) * 1024); }

    STAGE(0, 0)
    __syncthreads();

#pragma unroll 1
    for (int kb = 0; kb < 32; kb++) {
        int cur = kb & 1;
        if (kb < 31) STAGE(cur ^ 1, kb + 1)
        char* lb = smem + cur * 16384;
        // A fragments: m-tile m = 2*wm + m2 (region m), row lane15, fp32 blocks 2kg,2kg+1
        short8 af[2];
#pragma unroll
        for (int m2 = 0; m2 < 2; m2++) {
            char* rg = lb + (2 * wm + m2) * 2048 + lane15 * 16;
            float4 lo = *(const float4*)(rg + (2 * kg) * 256);
            float4 hi = *(const float4*)(rg + (2 * kg + 1) * 256);
            uint4 pk;
            pk.x = pack2(lo.x, lo.y); pk.y = pack2(lo.z, lo.w);
            pk.z = pack2(hi.x, hi.y); pk.w = pack2(hi.z, hi.w);
            af[m2] = __builtin_bit_cast(short8, pk);
        }
        // B fragments + MFMA
#pragma unroll
        for (int nt = 0; nt < 4; nt++) {
            uint4 bb = *(const uint4*)(lb + 8192 + (wn * 4 + nt) * 1024 + kg * 256 + lane15 * 16);
            short8 bf = __builtin_bit_cast(short8, bb);
#pragma unroll
            for (int m2 = 0; m2 < 2; m2++)
                acc[m2][nt] = __builtin_amdgcn_mfma_f32_16x16x32_bf16(af[m2], bf, acc[m2][nt], 0, 0, 0);
        }
        __syncthreads();
    }
#undef STAGE

    // epilogue: C[row][col], row = (2wm+m2)*16 + kg*4+j, col = wn*64 + nt*16 + lane15
#pragma unroll
    for (int m2 = 0; m2 < 2; m2++)
#pragma unroll
        for (int nt = 0; nt < 4; nt++) {
            int col = wn * 64 + nt * 16 + lane15;
            float bv = bias[col];
            int rbase = row0 + (2 * wm + m2) * 16 + kg * 4;
#pragma unroll
            for (int j = 0; j < 4; j++)
                out[(size_t)(rbase + j) * EMB + col] = acc[m2][nt][j] + bv;
        }
}

// ============ K3: rank/occ + direct table write (+hist) ============
__global__ __launch_bounds__(256) void ranktab_k(const int* __restrict__ s, const int* __restrict__ w,
                                                 const int* __restrict__ bhs, const int* __restrict__ bhw,
                                                 int* __restrict__ table, int* __restrict__ rank,
                                                 int* __restrict__ hist) {
    __shared__ int ll[256];
    int bx = blockIdx.x, z = bx >> 5, cb = bx & 31;
    const int* lab = z ? w : s;
    const int* bh = z ? bhw : bhs;
    int t = threadIdx.x;
    int j = cb * 256 + t;
    int c = lab[j];
    ll[t] = c;
    __syncthreads();
    int r = 0;
    for (int b = 0; b < cb; b++) r += bh[b * NC + c];
    for (int jj = 0; jj < t; jj++) r += (ll[jj] == c) ? 1 : 0;
    if (z) rank[j] = r;
    else   table[c * 8192 + r] = j;
    if (bx == 0 && t < 128) {
        int h = 0;
        if (t < NC)
            for (int b = 0; b < 32; b++) h += bhs[b * NC + t];
        hist[t] = h;
    }
}

// ============ K4: idx + lpos + l_neg (MFMA, register logits) + deferred softmax CE ========
// grid 512 x 256: 16 q-rows/block; 4 waves = 4 col-quarters (32 cols) of each 128-chunk.
// All 64 logits/lane kept in const-indexed register arrays; softmax ONE pass at end.
__global__ __launch_bounds__(256, 2) void ce_mfma_k(const float* __restrict__ q,
                                                    const float* __restrict__ k,
                                                    const ushort_t* __restrict__ Qt,
                                                    const int* __restrict__ rank,
                                                    const int* __restrict__ table,
                                                    const int* __restrict__ w,
                                                    const int* __restrict__ hist,
                                                    float* __restrict__ accum,
                                                    int* __restrict__ counter,
                                                    float* __restrict__ outp) {
    __shared__ int   idx_lds[16];
    __shared__ float lpos_lds[16];
    __shared__ float mg[4][16][2];
    int t = threadIdx.x;
    int r0 = blockIdx.x * 16;

    // inline idx: idx[i] = table[w[i]][rank[i] % cnt]
    if (t < 16) {
        int i = r0 + t;
        int c = w[i];
        int cc = hist[c];
        idx_lds[t] = (cc > 0) ? table[c * 8192 + (rank[i] % cc)] : 0;
    }
    __syncthreads();

    // fused l_pos (fp32 exact): row r0+(t>>4), 16 threads x 8 floats
    {
        int rr = t >> 4;
        int o = (t & 15) * 8;
        const float4* qa = (const float4*)(q + (size_t)(r0 + rr) * EMB + o);
        const float4* ka = (const float4*)(k + (size_t)idx_lds[rr] * EMB + o);
        float4 a0 = qa[0], b0 = ka[0], a1 = qa[1], b1 = ka[1];
        float s = a0.x * b0.x + a0.y * b0.y + a0.z * b0.z + a0.w * b0.w
                + a1.x * b1.x + a1.y * b1.y + a1.z * b1.z + a1.w * b1.w;
        s += __shfl_xor(s, 1); s += __shfl_xor(s, 2);
        s += __shfl_xor(s, 4); s += __shfl_xor(s, 8);
        if ((t & 15) == 0) lpos_lds[rr] = s;
    }

    int wv = t >> 6, ln = t & 63;
    int lane15 = ln & 15, kg = ln >> 4;

    // A-frags direct from q global (all waves same 16 rows)
    short8 afr[4];
#pragma unroll
    for (int ks = 0; ks < 4; ks++) {
        const float4* p = (const float4*)(q + (size_t)(r0 + lane15) * EMB + ks * 32 + kg * 8);
        float4 a = p[0], b = p[1];
        uint4 pk;
        pk.x = pack2(a.x, a.y); pk.y = pack2(a.z, a.w);
        pk.z = pack2(b.x, b.y); pk.w = pack2(b.z, b.w);
        afr[ks] = __builtin_bit_cast(short8, pk);
    }

    // all logits in registers: accA[nc] = cols wv*32+lane15, accB[nc] = +16
    f32x4 accA[8], accB[8];
#pragma unroll
    for (int nc = 0; nc < 8; nc++) {
        accA[nc] = (f32x4){0.f, 0.f, 0.f, 0.f};
        accB[nc] = (f32x4){0.f, 0.f, 0.f, 0.f};
    }
#pragma unroll
    for (int nc = 0; nc < 8; nc++) {
        size_t nrow0 = (size_t)(nc * 128 + wv * 32 + lane15) * 128 + kg * 8;
#pragma unroll
        for (int ks = 0; ks < 4; ks++) {
            short8 bf0 = __builtin_bit_cast(short8, *(const uint4*)(Qt + nrow0 + ks * 32));
            short8 bf1 = __builtin_bit_cast(short8, *(const uint4*)(Qt + nrow0 + 16 * 128 + ks * 32));
            accA[nc] = __builtin_amdgcn_mfma_f32_16x16x32_bf16(afr[ks], bf0, accA[nc], 0, 0, 0);
            accB[nc] = __builtin_amdgcn_mfma_f32_16x16x32_bf16(afr[ks], bf1, accB[nc], 0, 0, 0);
        }
    }

    // deferred softmax: one max/exp/sum pass over the 64 register logits
#pragma unroll
    for (int j = 0; j < 4; j++) {
        float mx = -1e30f;
#pragma unroll
        for (int nc = 0; nc < 8; nc++) mx = fmaxf(mx, fmaxf(accA[nc][j], accB[nc][j]));
        mx = fmaxf(mx, __shfl_xor(mx, 1));
        mx = fmaxf(mx, __shfl_xor(mx, 2));
        mx = fmaxf(mx, __shfl_xor(mx, 4));
        mx = fmaxf(mx, __shfl_xor(mx, 8));
        float s = 0.f;
#pragma unroll
        for (int nc = 0; nc < 8; nc++)
            s += __expf(accA[nc][j] - mx) + __expf(accB[nc][j] - mx);
        s += __shfl_xor(s, 1);
        s += __shfl_xor(s, 2);
        s += __shfl_xor(s, 4);
        s += __shfl_xor(s, 8);
        if (lane15 == 0) {
            mg[wv][kg * 4 + j][0] = mx;
            mg[wv][kg * 4 + j][1] = s;
        }
    }
    __syncthreads();
    if (wv == 0) {
        float cv = 0.f, cc = 0.f;
        if (t < 16) {
            int i = r0 + t;
            float m0 = mg[0][t][0], l0 = mg[0][t][1];
            float m1 = mg[1][t][0], l1 = mg[1][t][1];
            float m2 = mg[2][t][0], l2 = mg[2][t][1];
            float m3 = mg[3][t][0], l3 = mg[3][t][1];
            float lp = lpos_lds[t];
            float m = fmaxf(fmaxf(fmaxf(m0, m1), fmaxf(m2, m3)), lp);
            float l = l0 * __expf(m0 - m) + l1 * __expf(m1 - m)
                    + l2 * __expf(m2 - m) + l3 * __expf(m3 - m) + __expf(lp - m);
            float ce = -(lp - m - __logf(l));
            if (hist[w[i]] > 0) { cv = ce; cc = 1.f; }
        }
        cv += __shfl_xor(cv, 1);  cc += __shfl_xor(cc, 1);
        cv += __shfl_xor(cv, 2);  cc += __shfl_xor(cc, 2);
        cv += __shfl_xor(cv, 4);  cc += __shfl_xor(cc, 4);
        cv += __shfl_xor(cv, 8);  cc += __shfl_xor(cc, 8);
        if (t == 0) {
            atomicAdd(&accum[0], cv);
            atomicAdd(&accum[1], cc);
            __threadfence();
            int done = atomicAdd(counter, 1);
            if (done == 511) {   // last block finalizes
                float s = atomicAdd(&accum[0], 0.0f);
                float c = atomicAdd(&accum[1], 0.0f);
                outp[0] = s / fmaxf(c, 1.0f);
            }
        }
    }
}

extern "C" void kernel_launch(void* const* d_in, const int* in_sizes, int n_in,
                              void* d_out, int out_size, void* d_ws, size_t ws_size,
                              hipStream_t stream) {
    const float* feats_strong = (const float*)d_in[0];
    const float* feats_weak   = (const float*)d_in[1];
    const int*   s_lab        = (const int*)d_in[2];
    const int*   w_lab        = (const int*)d_in[3];
    const float* Wq           = (const float*)d_in[4];
    const float* bq           = (const float*)d_in[5];
    const float* Wk           = (const float*)d_in[6];
    const float* bk           = (const float*)d_in[7];
    const float* queue        = (const float*)d_in[8];

    float*    wsf = (float*)d_ws;
    int*      wsi = (int*)d_ws;

    float*    q_g   = wsf + OFF_Q;
    float*    k_g   = wsf + OFF_K;
    int*      table = wsi + OFF_TABLE;
    ushort_t* Wtq   = (ushort_t*)(wsi + OFF_WTQ);
    ushort_t* Wtk   = (ushort_t*)(wsi + OFF_WTK);
    int*      hist  = wsi + OFF_HIST;
    int*      rank  = wsi + OFF_RANK;
    int*      cnt   = wsi + OFF_CNT;
    int*      bhs   = wsi + OFF_BHS;
    int*      bhw   = wsi + OFF_BHW;
    float*    accum = wsf + OFF_ACC;
    ushort_t* Qt    = (ushort_t*)(wsi + OFF_QT);

    // K1: bf16 convert/transpose + label block-histograms + zero accum/counter
    cvtbh_k<<<448, 256, 0, stream>>>(Wq, Wk, queue, s_lab, w_lab,
                                     Wtq, Wtk, Qt, bhs, bhw, accum, cnt);
    // K2: both encoder GEMMs (m97 pattern; reads Wt region before K3 clobbers it)
    enc_mfma_k<<<256, 256, 0, stream>>>(feats_weak, feats_strong, Wtq, Wtk, bq, bk, q_g, k_g);
    // K3: rank + table + hist
    ranktab_k<<<64, 256, 0, stream>>>(s_lab, w_lab, bhs, bhw, table, rank, hist);
    // K4: idx + lpos + l_neg GEMM + CE + finalize
    ce_mfma_k<<<512, 256, 0, stream>>>(q_g, k_g, Qt, rank, table, w_lab, hist,
                                       accum, cnt, (float*)d_out);
}

// Round 10
// 178.079 us; speedup vs baseline: 1.0657x; 1.0401x over previous
//
#include <hip/hip_runtime.h>
#include <hip/hip_bf16.h>

// Problem constants (from reference)
#define NW   8192
#define NS   8192
#define FD   1024
#define EMB  128
#define QN   1024
#define NC   80

typedef unsigned short ushort_t;
typedef unsigned int   uint_t;
typedef __attribute__((ext_vector_type(8))) short short8;
typedef __attribute__((ext_vector_type(4))) float f32x4;

// ---------- workspace layout (element offsets, 4B units) ----------
#define OFF_Q      0u           // float [NW*EMB]
#define OFF_K      1048576u     // float [NS*EMB]
#define OFF_TABLE  2097152u     // int   [NC*8192] — aliases Wt (enc runs before ranktab)
#define OFF_WTQ    2097152u     // ushort[1024*128] (aliases table)
#define OFF_WTK    2129920u     // ushort[1024*128]
#define OFF_HIST   2752512u     // int   [128]
#define OFF_RANK   2752640u     // int   [NW]
#define OFF_CNT    2760832u     // int   [1] completion counter
#define OFF_BHS    2785408u     // int   [32*NC]
#define OFF_BHW    2787968u     // int   [32*NC]
#define OFF_ACC    2790528u     // float [2] : {sum_ce, valid_count}
#define OFF_QT     2790532u     // ushort[1024*128] (Qt: queue^T bf16)

__device__ __forceinline__ ushort_t f2bf(float f) {   // fp32 -> bf16 RNE
    uint_t u = __float_as_uint(f);
    u = (u + 0x7fffu + ((u >> 16) & 1u)) >> 16;
    return (ushort_t)u;
}
__device__ __forceinline__ uint_t pack2(float a, float b) {
    return (uint_t)f2bf(a) | ((uint_t)f2bf(b) << 16);
}

// async global->LDS, 16B per lane; LDS dest = WAVE-UNIFORM base + lane*16
#define GLOAD_LDS16(gp, lp)                                                     \
    __builtin_amdgcn_global_load_lds(                                           \
        (const __attribute__((address_space(1))) void*)(gp),                    \
        (__attribute__((address_space(3))) void*)(lp), 16, 0, 0)

// ============ K1: fused convert/transpose + per-block label histograms + init ============
__global__ __launch_bounds__(256) void cvtbh_k(const float* __restrict__ Wq,
                                               const float* __restrict__ Wk,
                                               const float* __restrict__ queue,
                                               const int* __restrict__ s_lab,
                                               const int* __restrict__ w_lab,
                                               ushort_t* __restrict__ Wtq,
                                               ushort_t* __restrict__ Wtk,
                                               ushort_t* __restrict__ Qt,
                                               int* __restrict__ bhs,
                                               int* __restrict__ bhw,
                                               float* __restrict__ accum,
                                               int* __restrict__ counter) {
    int bx = blockIdx.x;
    int t = threadIdx.x;
    if (bx >= 384) {   // ---- bh part ----
        __shared__ int h[NC];
        int b2 = bx - 384, z = b2 >> 5, cb = b2 & 31;
        const int* lab = z ? w_lab : s_lab;
        int* bh = z ? bhw : bhs;
        if (t < NC) h[t] = 0;
        __syncthreads();
        atomicAdd(&h[lab[cb * 256 + t]], 1);
        __syncthreads();
        if (t < NC) bh[cb * NC + t] = h[t];
        return;
    }
    // ---- cvt part ----
    __shared__ float tile[32][33];
    int z = bx >> 7, flat = bx & 127;
    if (z == 0 && flat == 0) {
        if (t < 2) accum[t] = 0.0f;
        if (t == 2) *counter = 0;
    }
    const float* in; ushort_t* out; int r0, c0, C;
    if (z < 2) { in = z ? Wk : Wq; out = z ? Wtk : Wtq; C = 128;
                 r0 = (flat >> 2) * 32; c0 = (flat & 3) * 32; }
    else       { in = queue; out = Qt; C = 1024;
                 r0 = (flat & 3) * 32; c0 = (flat >> 2) * 32; }
    int i = t >> 3, j0 = (t & 7) * 4;
    float4 v = *(const float4*)(in + (size_t)(r0 + i) * C + c0 + j0);
    tile[i][j0] = v.x; tile[i][j0 + 1] = v.y; tile[i][j0 + 2] = v.z; tile[i][j0 + 3] = v.w;
    __syncthreads();
    uint2 pk;
    pk.x = pack2(tile[j0][i], tile[j0 + 1][i]);
    pk.y = pack2(tile[j0 + 2][i], tile[j0 + 3][i]);
    size_t oaddr;
    if (z < 2) oaddr = ((size_t)(r0 >> 5) * 128 + (c0 + i)) * 32 + j0;   // tiled [kb][n][kk]
    else       oaddr = (size_t)(c0 + i) * 128 + (r0 + j0);               // plain [n][k]
    *(uint2*)(out + oaddr) = pk;
}

// ============ K2: encoder GEMM — global_load_lds dbuf, 16x128 tiles, 4 blocks/CU ==========
// grid 1024: bx>>9 = encoder, bx&511 = 16-row tile. 4 waves N-split (wave wv -> cols wv*32..+31).
// LDS/buf = 10KB: A 2KB (16 rows x 32k fp32, 16B slots XOR-swizzled: slot = r*8 + (c ^ (r&7)))
//                 B 8KB ([n][kk] bf16, slot = n*4 + c) — both DMA-contiguous AND ds_read bank-even.
__global__ __launch_bounds__(256) void enc_mfma_k(const float* __restrict__ A0,
                                                  const float* __restrict__ A1,
                                                  const ushort_t* __restrict__ Wt0,
                                                  const ushort_t* __restrict__ Wt1,
                                                  const float* __restrict__ b0_,
                                                  const float* __restrict__ b1_,
                                                  float* __restrict__ out0,
                                                  float* __restrict__ out1) {
    __shared__ __align__(16) char smem[20480];   // 2 x (2KB A + 8KB B)

    int bx = blockIdx.x;
    int which = bx >> 9;
    int mtile = bx & 511;
    const float*    A    = which ? A1 : A0;
    const ushort_t* Wt   = which ? Wt1 : Wt0;
    const float*    bias = which ? b1_ : b0_;
    float*          out  = which ? out1 : out0;
    int row0 = mtile * 16;

    int t = threadIdx.x;
    int wv = t >> 6, ln = t & 63;
    int lane15 = ln & 15, kg = ln >> 4;

    // --- staging global bases (k-invariant) ---
    // A (waves 0,1 only): lane ln -> row wv*8 + (ln>>3), swizzled chunk ((ln&7)^((ln>>3)&7))
    int arow_l = (wv & 1) * 8 + (ln >> 3);
    const float* gA = A + (size_t)(row0 + arow_l) * FD + ((ln & 7) ^ ((ln >> 3) & 7)) * 4;
    // B (all waves, 2 instrs): lane ln -> n = wv*32 + j*16 + (ln>>2), chunk c = ln&3
    const ushort_t* gB0 = Wt + (size_t)(wv * 32 + (ln >> 2)) * 32 + (ln & 3) * 8;
    const ushort_t* gB1 = Wt + (size_t)(wv * 32 + 16 + (ln >> 2)) * 32 + (ln & 3) * 8;

    f32x4 acc0 = (f32x4){0.f, 0.f, 0.f, 0.f};
    f32x4 acc1 = (f32x4){0.f, 0.f, 0.f, 0.f};

#define STAGE(BUF, KB)                                                          \
    { char* lb = smem + (BUF) * 10240;                                          \
      if (wv < 2) GLOAD_LDS16(gA + (size_t)(KB) * 32, lb + wv * 1024);          \
      GLOAD_LDS16(gB0 + (size_t)(KB) * 4096, lb + 2048 + wv * 2048);            \
      GLOAD_LDS16(gB1 + (size_t)(KB) * 4096, lb + 2048 + wv * 2048 + 1024); }

    STAGE(0, 0)
    __syncthreads();

#pragma unroll 1
    for (int kb = 0; kb < 32; kb++) {
        int cur = kb & 1;
        if (kb < 31) STAGE(cur ^ 1, kb + 1)
        char* lb = smem + cur * 10240;
        // A frag: row lane15, k = kg*8..+7 (chunks 2kg, 2kg+1, XOR-swizzled)
        float4 alo = *(const float4*)(lb + (lane15 * 8 + ((2 * kg)     ^ (lane15 & 7))) * 16);
        float4 ahi = *(const float4*)(lb + (lane15 * 8 + ((2 * kg + 1) ^ (lane15 & 7))) * 16);
        uint4 pk;
        pk.x = pack2(alo.x, alo.y); pk.y = pack2(alo.z, alo.w);
        pk.z = pack2(ahi.x, ahi.y); pk.w = pack2(ahi.z, ahi.w);
        short8 af = __builtin_bit_cast(short8, pk);
        // B frags: n = wv*32 + nt*16 + lane15, chunk kg
        uint4 bb0 = *(const uint4*)(lb + 2048 + (wv * 128 +      lane15 * 4 + kg) * 16);
        uint4 bb1 = *(const uint4*)(lb + 2048 + (wv * 128 + 64 + lane15 * 4 + kg) * 16);
        acc0 = __builtin_amdgcn_mfma_f32_16x16x32_bf16(af, __builtin_bit_cast(short8, bb0), acc0, 0, 0, 0);
        acc1 = __builtin_amdgcn_mfma_f32_16x16x32_bf16(af, __builtin_bit_cast(short8, bb1), acc1, 0, 0, 0);
        __syncthreads();
    }
#undef STAGE

    // epilogue: C[row][col], row = row0 + kg*4+j, col = wv*32 + {0,16} + lane15
    {
        int col0 = wv * 32 + lane15, col1 = wv * 32 + 16 + lane15;
        float bv0 = bias[col0], bv1 = bias[col1];
        int rbase = row0 + kg * 4;
#pragma unroll
        for (int j = 0; j < 4; j++) {
            out[(size_t)(rbase + j) * EMB + col0] = acc0[j] + bv0;
            out[(size_t)(rbase + j) * EMB + col1] = acc1[j] + bv1;
        }
    }
}

// ============ K3: rank/occ + direct table write (+hist) ============
__global__ __launch_bounds__(256) void ranktab_k(const int* __restrict__ s, const int* __restrict__ w,
                                                 const int* __restrict__ bhs, const int* __restrict__ bhw,
                                                 int* __restrict__ table, int* __restrict__ rank,
                                                 int* __restrict__ hist) {
    __shared__ int ll[256];
    int bx = blockIdx.x, z = bx >> 5, cb = bx & 31;
    const int* lab = z ? w : s;
    const int* bh = z ? bhw : bhs;
    int t = threadIdx.x;
    int j = cb * 256 + t;
    int c = lab[j];
    ll[t] = c;
    __syncthreads();
    int r = 0;
    for (int b = 0; b < cb; b++) r += bh[b * NC + c];
    for (int jj = 0; jj < t; jj++) r += (ll[jj] == c) ? 1 : 0;
    if (z) rank[j] = r;
    else   table[c * 8192 + r] = j;
    if (bx == 0 && t < 128) {
        int h = 0;
        if (t < NC)
            for (int b = 0; b < 32; b++) h += bhs[b * NC + t];
        hist[t] = h;
    }
}

// ============ K4: idx + lpos + l_neg (MFMA, register logits) + deferred softmax CE ========
// grid 512 x 256: 16 q-rows/block; 4 waves = 4 col-quarters (32 cols) of each 128-chunk.
__global__ __launch_bounds__(256, 2) void ce_mfma_k(const float* __restrict__ q,
                                                    const float* __restrict__ k,
                                                    const ushort_t* __restrict__ Qt,
                                                    const int* __restrict__ rank,
                                                    const int* __restrict__ table,
                                                    const int* __restrict__ w,
                                                    const int* __restrict__ hist,
                                                    float* __restrict__ accum,
                                                    int* __restrict__ counter,
                                                    float* __restrict__ outp) {
    __shared__ int   idx_lds[16];
    __shared__ float lpos_lds[16];
    __shared__ float mg[4][16][2];
    int t = threadIdx.x;
    int r0 = blockIdx.x * 16;

    // inline idx: idx[i] = table[w[i]][rank[i] % cnt]
    if (t < 16) {
        int i = r0 + t;
        int c = w[i];
        int cc = hist[c];
        idx_lds[t] = (cc > 0) ? table[c * 8192 + (rank[i] % cc)] : 0;
    }
    __syncthreads();

    // fused l_pos (fp32 exact): row r0+(t>>4), 16 threads x 8 floats
    {
        int rr = t >> 4;
        int o = (t & 15) * 8;
        const float4* qa = (const float4*)(q + (size_t)(r0 + rr) * EMB + o);
        const float4* ka = (const float4*)(k + (size_t)idx_lds[rr] * EMB + o);
        float4 a0 = qa[0], b0 = ka[0], a1 = qa[1], b1 = ka[1];
        float s = a0.x * b0.x + a0.y * b0.y + a0.z * b0.z + a0.w * b0.w
                + a1.x * b1.x + a1.y * b1.y + a1.z * b1.z + a1.w * b1.w;
        s += __shfl_xor(s, 1); s += __shfl_xor(s, 2);
        s += __shfl_xor(s, 4); s += __shfl_xor(s, 8);
        if ((t & 15) == 0) lpos_lds[rr] = s;
    }

    int wv = t >> 6, ln = t & 63;
    int lane15 = ln & 15, kg = ln >> 4;

    // A-frags direct from q global (all waves same 16 rows)
    short8 afr[4];
#pragma unroll
    for (int ks = 0; ks < 4; ks++) {
        const float4* p = (const float4*)(q + (size_t)(r0 + lane15) * EMB + ks * 32 + kg * 8);
        float4 a = p[0], b = p[1];
        uint4 pk;
        pk.x = pack2(a.x, a.y); pk.y = pack2(a.z, a.w);
        pk.z = pack2(b.x, b.y); pk.w = pack2(b.z, b.w);
        afr[ks] = __builtin_bit_cast(short8, pk);
    }

    // all logits in registers: accA[nc] = cols wv*32+lane15, accB[nc] = +16
    f32x4 accA[8], accB[8];
#pragma unroll
    for (int nc = 0; nc < 8; nc++) {
        accA[nc] = (f32x4){0.f, 0.f, 0.f, 0.f};
        accB[nc] = (f32x4){0.f, 0.f, 0.f, 0.f};
    }
#pragma unroll
    for (int nc = 0; nc < 8; nc++) {
        size_t nrow0 = (size_t)(nc * 128 + wv * 32 + lane15) * 128 + kg * 8;
#pragma unroll
        for (int ks = 0; ks < 4; ks++) {
            short8 bf0 = __builtin_bit_cast(short8, *(const uint4*)(Qt + nrow0 + ks * 32));
            short8 bf1 = __builtin_bit_cast(short8, *(const uint4*)(Qt + nrow0 + 16 * 128 + ks * 32));
            accA[nc] = __builtin_amdgcn_mfma_f32_16x16x32_bf16(afr[ks], bf0, accA[nc], 0, 0, 0);
            accB[nc] = __builtin_amdgcn_mfma_f32_16x16x32_bf16(afr[ks], bf1, accB[nc], 0, 0, 0);
        }
    }

    // deferred softmax: one max/exp/sum pass over the 64 register logits
#pragma unroll
    for (int j = 0; j < 4; j++) {
        float mx = -1e30f;
#pragma unroll
        for (int nc = 0; nc < 8; nc++) mx = fmaxf(mx, fmaxf(accA[nc][j], accB[nc][j]));
        mx = fmaxf(mx, __shfl_xor(mx, 1));
        mx = fmaxf(mx, __shfl_xor(mx, 2));
        mx = fmaxf(mx, __shfl_xor(mx, 4));
        mx = fmaxf(mx, __shfl_xor(mx, 8));
        float s = 0.f;
#pragma unroll
        for (int nc = 0; nc < 8; nc++)
            s += __expf(accA[nc][j] - mx) + __expf(accB[nc][j] - mx);
        s += __shfl_xor(s, 1);
        s += __shfl_xor(s, 2);
        s += __shfl_xor(s, 4);
        s += __shfl_xor(s, 8);
        if (lane15 == 0) {
            mg[wv][kg * 4 + j][0] = mx;
            mg[wv][kg * 4 + j][1] = s;
        }
    }
    __syncthreads();
    if (wv == 0) {
        float cv = 0.f, cc = 0.f;
        if (t < 16) {
            int i = r0 + t;
            float m0 = mg[0][t][0], l0 = mg[0][t][1];
            float m1 = mg[1][t][0], l1 = mg[1][t][1];
            float m2 = mg[2][t][0], l2 = mg[2][t][1];
            float m3 = mg[3][t][0], l3 = mg[3][t][1];
            float lp = lpos_lds[t];
            float m = fmaxf(fmaxf(fmaxf(m0, m1), fmaxf(m2, m3)), lp);
            float l = l0 * __expf(m0 - m) + l1 * __expf(m1 - m)
                    + l2 * __expf(m2 - m) + l3 * __expf(m3 - m) + __expf(lp - m);
            float ce = -(lp - m - __logf(l));
            if (hist[w[i]] > 0) { cv = ce; cc = 1.f; }
        }
        cv += __shfl_xor(cv, 1);  cc += __shfl_xor(cc, 1);
        cv += __shfl_xor(cv, 2);  cc += __shfl_xor(cc, 2);
        cv += __shfl_xor(cv, 4);  cc += __shfl_xor(cc, 4);
        cv += __shfl_xor(cv, 8);  cc += __shfl_xor(cc, 8);
        if (t == 0) {
            atomicAdd(&accum[0], cv);
            atomicAdd(&accum[1], cc);
            __threadfence();
            int done = atomicAdd(counter, 1);
            if (done == 511) {   // last block finalizes
                float s = atomicAdd(&accum[0], 0.0f);
                float c = atomicAdd(&accum[1], 0.0f);
                outp[0] = s / fmaxf(c, 1.0f);
            }
        }
    }
}

extern "C" void kernel_launch(void* const* d_in, const int* in_sizes, int n_in,
                              void* d_out, int out_size, void* d_ws, size_t ws_size,
                              hipStream_t stream) {
    const float* feats_strong = (const float*)d_in[0];
    const float* feats_weak   = (const float*)d_in[1];
    const int*   s_lab        = (const int*)d_in[2];
    const int*   w_lab        = (const int*)d_in[3];
    const float* Wq           = (const float*)d_in[4];
    const float* bq           = (const float*)d_in[5];
    const float* Wk           = (const float*)d_in[6];
    const float* bk           = (const float*)d_in[7];
    const float* queue        = (const float*)d_in[8];

    float*    wsf = (float*)d_ws;
    int*      wsi = (int*)d_ws;

    float*    q_g   = wsf + OFF_Q;
    float*    k_g   = wsf + OFF_K;
    int*      table = wsi + OFF_TABLE;
    ushort_t* Wtq   = (ushort_t*)(wsi + OFF_WTQ);
    ushort_t* Wtk   = (ushort_t*)(wsi + OFF_WTK);
    int*      hist  = wsi + OFF_HIST;
    int*      rank  = wsi + OFF_RANK;
    int*      cnt   = wsi + OFF_CNT;
    int*      bhs   = wsi + OFF_BHS;
    int*      bhw   = wsi + OFF_BHW;
    float*    accum = wsf + OFF_ACC;
    ushort_t* Qt    = (ushort_t*)(wsi + OFF_QT);

    // K1: bf16 convert/transpose + label block-histograms + zero accum/counter
    cvtbh_k<<<448, 256, 0, stream>>>(Wq, Wk, queue, s_lab, w_lab,
                                     Wtq, Wtk, Qt, bhs, bhw, accum, cnt);
    // K2: both encoder GEMMs (reads Wt region before K3 clobbers it)
    enc_mfma_k<<<1024, 256, 0, stream>>>(feats_weak, feats_strong, Wtq, Wtk, bq, bk, q_g, k_g);
    // K3: rank + table + hist
    ranktab_k<<<64, 256, 0, stream>>>(s_lab, w_lab, bhs, bhw, table, rank, hist);
    // K4: idx + lpos + l_neg GEMM + CE + finalize
    ce_mfma_k<<<512, 256, 0, stream>>>(q_g, k_g, Qt, rank, table, w_lab, hist,
                                       accum, cnt, (float*)d_out);
}

// Round 11
// 169.672 us; speedup vs baseline: 1.1185x; 1.0495x over previous
//
#include <hip/hip_runtime.h>
#include <hip/hip_bf16.h>

// Problem constants (from reference)
#define NW   8192
#define NS   8192
#define FD   1024
#define EMB  128
#define QN   1024
#define NC   80

typedef unsigned short ushort_t;
typedef unsigned int   uint_t;
typedef __attribute__((ext_vector_type(8))) short short8;
typedef __attribute__((ext_vector_type(4))) float f32x4;

// ---------- workspace layout (element offsets, 4B units) ----------
#define OFF_Q      0u           // float [NW*EMB]
#define OFF_K      1048576u     // float [NS*EMB]
#define OFF_TABLE  2097152u     // int   [NC*8192] — aliases Wt (enc runs before ranktab)
#define OFF_WTQ    2097152u     // ushort[1024*128] (aliases table)
#define OFF_WTK    2129920u     // ushort[1024*128]
#define OFF_HIST   2752512u     // int   [128]
#define OFF_RANK   2752640u     // int   [NW]
#define OFF_CNT    2760832u     // int   [1] completion counter
#define OFF_BHS    2785408u     // int   [32*NC]
#define OFF_BHW    2787968u     // int   [32*NC]
#define OFF_ACC    2790528u     // float [2] : {sum_ce, valid_count}
#define OFF_QT     2790532u     // ushort[1024*128] (Qt: queue^T bf16)

__device__ __forceinline__ ushort_t f2bf(float f) {   // fp32 -> bf16 RNE
    uint_t u = __float_as_uint(f);
    u = (u + 0x7fffu + ((u >> 16) & 1u)) >> 16;
    return (ushort_t)u;
}
__device__ __forceinline__ uint_t pack2(float a, float b) {
    return (uint_t)f2bf(a) | ((uint_t)f2bf(b) << 16);
}

// async global->LDS, 16B per lane; LDS dest = WAVE-UNIFORM base + lane*16 (no per-lane scatter)
#define GLOAD_LDS16(gp, lp)                                                     \
    __builtin_amdgcn_global_load_lds(                                           \
        (const __attribute__((address_space(1))) void*)(gp),                    \
        (__attribute__((address_space(3))) void*)(lp), 16, 0, 0)

// ============ K1: fused convert/transpose + per-block label histograms + init ============
// z<2: W[1024][128] -> Wt tiled [kb(16)][kg(8)][n(128)][8]  (kb=k>>6, kg=(k>>3)&7)
// z=2: queue[128][1024] -> Qt[n][k] plain
__global__ __launch_bounds__(256) void cvtbh_k(const float* __restrict__ Wq,
                                               const float* __restrict__ Wk,
                                               const float* __restrict__ queue,
                                               const int* __restrict__ s_lab,
                                               const int* __restrict__ w_lab,
                                               ushort_t* __restrict__ Wtq,
                                               ushort_t* __restrict__ Wtk,
                                               ushort_t* __restrict__ Qt,
                                               int* __restrict__ bhs,
                                               int* __restrict__ bhw,
                                               float* __restrict__ accum,
                                               int* __restrict__ counter) {
    int bx = blockIdx.x;
    int t = threadIdx.x;
    if (bx >= 384) {   // ---- bh part ----
        __shared__ int h[NC];
        int b2 = bx - 384, z = b2 >> 5, cb = b2 & 31;
        const int* lab = z ? w_lab : s_lab;
        int* bh = z ? bhw : bhs;
        if (t < NC) h[t] = 0;
        __syncthreads();
        atomicAdd(&h[lab[cb * 256 + t]], 1);
        __syncthreads();
        if (t < NC) bh[cb * NC + t] = h[t];
        return;
    }
    // ---- cvt part ----
    __shared__ float tile[32][33];
    int z = bx >> 7, flat = bx & 127;
    if (z == 0 && flat == 0) {
        if (t < 2) accum[t] = 0.0f;
        if (t == 2) *counter = 0;
    }
    const float* in; ushort_t* out; int r0, c0, C;
    if (z < 2) { in = z ? Wk : Wq; out = z ? Wtk : Wtq; C = 128;
                 r0 = (flat >> 2) * 32; c0 = (flat & 3) * 32; }
    else       { in = queue; out = Qt; C = 1024;
                 r0 = (flat & 3) * 32; c0 = (flat >> 2) * 32; }
    int i = t >> 3, j0 = (t & 7) * 4;
    float4 v = *(const float4*)(in + (size_t)(r0 + i) * C + c0 + j0);
    tile[i][j0] = v.x; tile[i][j0 + 1] = v.y; tile[i][j0 + 2] = v.z; tile[i][j0 + 3] = v.w;
    __syncthreads();
    uint2 pk;
    pk.x = pack2(tile[j0][i], tile[j0 + 1][i]);
    pk.y = pack2(tile[j0 + 2][i], tile[j0 + 3][i]);
    size_t oaddr;
    if (z < 2) {
        int k0 = r0 + j0, n = c0 + i;   // 4 consecutive k at (k0..k0+3), n fixed
        oaddr = (size_t)(k0 >> 6) * 8192 + (size_t)((k0 >> 3) & 7) * 1024
              + (size_t)n * 8 + (k0 & 7);
    } else {
        oaddr = (size_t)(c0 + i) * 128 + (r0 + j0);   // plain [n][k]
    }
    *(uint2*)(out + oaddr) = pk;
}

// ============ K2: encoder GEMM — global_load_lds dbuf, BK=64, conflict-free LDS ==========
// grid 1024: bx>>9 = encoder, bx&511 = 16-row tile. 4 waves N-split (wave wv -> cols wv*32..+31).
// LDS/buf = 20KB: A 4KB (16 rows x 16 chunks of 4 fp32; chunk stored at slot r*16 + (c^r),
//   achieved by XOR-swizzling the GLOBAL gather so DMA dest stays uniform+lane*16),
//   reader banks: ((c^r)*4)&31 -> 2-way per 16-lane phase (free).
// B 16KB ([kg(8)][n(128)] 16B slots, from Wt tiled [kb][kg][n][8]) — DMA linear,
//   reader banks: (n*4)&31 -> 2-way per phase (free). 16 barriers (BK=64). 4 blocks/CU.
__global__ __launch_bounds__(256) void enc_mfma_k(const float* __restrict__ A0,
                                                  const float* __restrict__ A1,
                                                  const ushort_t* __restrict__ Wt0,
                                                  const ushort_t* __restrict__ Wt1,
                                                  const float* __restrict__ b0_,
                                                  const float* __restrict__ b1_,
                                                  float* __restrict__ out0,
                                                  float* __restrict__ out1) {
    __shared__ __align__(16) char smem[40960];   // 2 x (4KB A + 16KB B)

    int bx = blockIdx.x;
    int which = bx >> 9;
    int mtile = bx & 511;
    const float*    A    = which ? A1 : A0;
    const ushort_t* Wt   = which ? Wt1 : Wt0;
    const float*    bias = which ? b1_ : b0_;
    float*          out  = which ? out1 : out0;
    int row0 = mtile * 16;

    int t = threadIdx.x;
    int wv = t >> 6, ln = t & 63;
    int lane15 = ln & 15, kg = ln >> 4;

    // --- A staging base: wave wv stages rows wv*4..+3; lane ln -> row r, XOR'd chunk c ---
    int ar = wv * 4 + (ln >> 4);
    int ac = (ln & 15) ^ (ar & 15);
    const float* gA = A + (size_t)(row0 + ar) * FD + ac * 4;
    // --- B staging base: wave wv, instr i -> slots (wv*4+i)*64 + ln; linear in tiled Wt ---
    const ushort_t* gB = Wt + (size_t)wv * 2048 + ln * 8;

    f32x4 acc0 = (f32x4){0.f, 0.f, 0.f, 0.f};
    f32x4 acc1 = (f32x4){0.f, 0.f, 0.f, 0.f};

#define STAGE(BUF, KB)                                                           \
    { char* lb = smem + (BUF) * 20480;                                           \
      GLOAD_LDS16(gA + (size_t)(KB) * 64, lb + wv * 1024);                       \
      const ushort_t* gb = gB + (size_t)(KB) * 8192;                             \
      char* bb = lb + 4096 + wv * 4096;                                          \
      GLOAD_LDS16(gb,        bb);                                                \
      GLOAD_LDS16(gb + 512,  bb + 1024);                                         \
      GLOAD_LDS16(gb + 1024, bb + 2048);                                         \
      GLOAD_LDS16(gb + 1536, bb + 3072); }

    STAGE(0, 0)
    __syncthreads();

#pragma unroll 1
    for (int kb = 0; kb < 16; kb++) {
        int cur = kb & 1;
        if (kb < 15) STAGE(cur ^ 1, kb + 1)
        char* lb = smem + cur * 20480;
#pragma unroll
        for (int ks = 0; ks < 2; ks++) {
            // A frag: row lane15, chunks c0 = ks*8 + kg*2, c0+1 (XOR-swizzled slots)
            int c0 = ks * 8 + kg * 2;
            float4 alo = *(const float4*)(lb + (lane15 * 16 + ((c0)     ^ lane15)) * 16);
            float4 ahi = *(const float4*)(lb + (lane15 * 16 + ((c0 + 1) ^ lane15)) * 16);
            uint4 pk;
            pk.x = pack2(alo.x, alo.y); pk.y = pack2(alo.z, alo.w);
            pk.z = pack2(ahi.x, ahi.y); pk.w = pack2(ahi.z, ahi.w);
            short8 af = __builtin_bit_cast(short8, pk);
            // B frags: slot = (ks*4+kg)*128 + n,  n = wv*32 + {0,16} + lane15
            int kgg = ks * 4 + kg;
            uint4 bb0 = *(const uint4*)(lb + 4096 + ((size_t)kgg * 128 + wv * 32 + lane15) * 16);
            uint4 bb1 = *(const uint4*)(lb + 4096 + ((size_t)kgg * 128 + wv * 32 + 16 + lane15) * 16);
            acc0 = __builtin_amdgcn_mfma_f32_16x16x32_bf16(af, __builtin_bit_cast(short8, bb0), acc0, 0, 0, 0);
            acc1 = __builtin_amdgcn_mfma_f32_16x16x32_bf16(af, __builtin_bit_cast(short8, bb1), acc1, 0, 0, 0);
        }
        __syncthreads();
    }
#undef STAGE

    // epilogue: C[row][col], row = row0 + kg*4+j, col = wv*32 + {0,16} + lane15
    {
        int col0 = wv * 32 + lane15, col1 = wv * 32 + 16 + lane15;
        float bv0 = bias[col0], bv1 = bias[col1];
        int rbase = row0 + kg * 4;
#pragma unroll
        for (int j = 0; j < 4; j++) {
            out[(size_t)(rbase + j) * EMB + col0] = acc0[j] + bv0;
            out[(size_t)(rbase + j) * EMB + col1] = acc1[j] + bv1;
        }
    }
}

// ============ K3: rank/occ + direct table write (+hist) ============
__global__ __launch_bounds__(256) void ranktab_k(const int* __restrict__ s, const int* __restrict__ w,
                                                 const int* __restrict__ bhs, const int* __restrict__ bhw,
                                                 int* __restrict__ table, int* __restrict__ rank,
                                                 int* __restrict__ hist) {
    __shared__ int ll[256];
    int bx = blockIdx.x, z = bx >> 5, cb = bx & 31;
    const int* lab = z ? w : s;
    const int* bh = z ? bhw : bhs;
    int t = threadIdx.x;
    int j = cb * 256 + t;
    int c = lab[j];
    ll[t] = c;
    __syncthreads();
    int r = 0;
    for (int b = 0; b < cb; b++) r += bh[b * NC + c];
    for (int jj = 0; jj < t; jj++) r += (ll[jj] == c) ? 1 : 0;
    if (z) rank[j] = r;
    else   table[c * 8192 + r] = j;
    if (bx == 0 && t < 128) {
        int h = 0;
        if (t < NC)
            for (int b = 0; b < 32; b++) h += bhs[b * NC + t];
        hist[t] = h;
    }
}

// ============ K4: idx + lpos + l_neg (MFMA, register logits) + deferred softmax CE ========
// grid 512 x 256: 16 q-rows/block; 4 waves = 4 col-quarters (32 cols) of each 128-chunk.
__global__ __launch_bounds__(256, 2) void ce_mfma_k(const float* __restrict__ q,
                                                    const float* __restrict__ k,
                                                    const ushort_t* __restrict__ Qt,
                                                    const int* __restrict__ rank,
                                                    const int* __restrict__ table,
                                                    const int* __restrict__ w,
                                                    const int* __restrict__ hist,
                                                    float* __restrict__ accum,
                                                    int* __restrict__ counter,
                                                    float* __restrict__ outp) {
    __shared__ int   idx_lds[16];
    __shared__ float lpos_lds[16];
    __shared__ float mg[4][16][2];
    int t = threadIdx.x;
    int r0 = blockIdx.x * 16;

    // inline idx: idx[i] = table[w[i]][rank[i] % cnt]
    if (t < 16) {
        int i = r0 + t;
        int c = w[i];
        int cc = hist[c];
        idx_lds[t] = (cc > 0) ? table[c * 8192 + (rank[i] % cc)] : 0;
    }
    __syncthreads();

    // fused l_pos (fp32 exact): row r0+(t>>4), 16 threads x 8 floats
    {
        int rr = t >> 4;
        int o = (t & 15) * 8;
        const float4* qa = (const float4*)(q + (size_t)(r0 + rr) * EMB + o);
        const float4* ka = (const float4*)(k + (size_t)idx_lds[rr] * EMB + o);
        float4 a0 = qa[0], b0 = ka[0], a1 = qa[1], b1 = ka[1];
        float s = a0.x * b0.x + a0.y * b0.y + a0.z * b0.z + a0.w * b0.w
                + a1.x * b1.x + a1.y * b1.y + a1.z * b1.z + a1.w * b1.w;
        s += __shfl_xor(s, 1); s += __shfl_xor(s, 2);
        s += __shfl_xor(s, 4); s += __shfl_xor(s, 8);
        if ((t & 15) == 0) lpos_lds[rr] = s;
    }

    int wv = t >> 6, ln = t & 63;
    int lane15 = ln & 15, kg = ln >> 4;

    // A-frags direct from q global (all waves same 16 rows)
    short8 afr[4];
#pragma unroll
    for (int ks = 0; ks < 4; ks++) {
        const float4* p = (const float4*)(q + (size_t)(r0 + lane15) * EMB + ks * 32 + kg * 8);
        float4 a = p[0], b = p[1];
        uint4 pk;
        pk.x = pack2(a.x, a.y); pk.y = pack2(a.z, a.w);
        pk.z = pack2(b.x, b.y); pk.w = pack2(b.z, b.w);
        afr[ks] = __builtin_bit_cast(short8, pk);
    }

    // all logits in registers: accA[nc] = cols wv*32+lane15, accB[nc] = +16
    f32x4 accA[8], accB[8];
#pragma unroll
    for (int nc = 0; nc < 8; nc++) {
        accA[nc] = (f32x4){0.f, 0.f, 0.f, 0.f};
        accB[nc] = (f32x4){0.f, 0.f, 0.f, 0.f};
    }
#pragma unroll
    for (int nc = 0; nc < 8; nc++) {
        size_t nrow0 = (size_t)(nc * 128 + wv * 32 + lane15) * 128 + kg * 8;
#pragma unroll
        for (int ks = 0; ks < 4; ks++) {
            short8 bf0 = __builtin_bit_cast(short8, *(const uint4*)(Qt + nrow0 + ks * 32));
            short8 bf1 = __builtin_bit_cast(short8, *(const uint4*)(Qt + nrow0 + 16 * 128 + ks * 32));
            accA[nc] = __builtin_amdgcn_mfma_f32_16x16x32_bf16(afr[ks], bf0, accA[nc], 0, 0, 0);
            accB[nc] = __builtin_amdgcn_mfma_f32_16x16x32_bf16(afr[ks], bf1, accB[nc], 0, 0, 0);
        }
    }

    // deferred softmax: one max/exp/sum pass over the 64 register logits
#pragma unroll
    for (int j = 0; j < 4; j++) {
        float mx = -1e30f;
#pragma unroll
        for (int nc = 0; nc < 8; nc++) mx = fmaxf(mx, fmaxf(accA[nc][j], accB[nc][j]));
        mx = fmaxf(mx, __shfl_xor(mx, 1));
        mx = fmaxf(mx, __shfl_xor(mx, 2));
        mx = fmaxf(mx, __shfl_xor(mx, 4));
        mx = fmaxf(mx, __shfl_xor(mx, 8));
        float s = 0.f;
#pragma unroll
        for (int nc = 0; nc < 8; nc++)
            s += __expf(accA[nc][j] - mx) + __expf(accB[nc][j] - mx);
        s += __shfl_xor(s, 1);
        s += __shfl_xor(s, 2);
        s += __shfl_xor(s, 4);
        s += __shfl_xor(s, 8);
        if (lane15 == 0) {
            mg[wv][kg * 4 + j][0] = mx;
            mg[wv][kg * 4 + j][1] = s;
        }
    }
    __syncthreads();
    if (wv == 0) {
        float cv = 0.f, cc = 0.f;
        if (t < 16) {
            int i = r0 + t;
            float m0 = mg[0][t][0], l0 = mg[0][t][1];
            float m1 = mg[1][t][0], l1 = mg[1][t][1];
            float m2 = mg[2][t][0], l2 = mg[2][t][1];
            float m3 = mg[3][t][0], l3 = mg[3][t][1];
            float lp = lpos_lds[t];
            float m = fmaxf(fmaxf(fmaxf(m0, m1), fmaxf(m2, m3)), lp);
            float l = l0 * __expf(m0 - m) + l1 * __expf(m1 - m)
                    + l2 * __expf(m2 - m) + l3 * __expf(m3 - m) + __expf(lp - m);
            float ce = -(lp - m - __logf(l));
            if (hist[w[i]] > 0) { cv = ce; cc = 1.f; }
        }
        cv += __shfl_xor(cv, 1);  cc += __shfl_xor(cc, 1);
        cv += __shfl_xor(cv, 2);  cc += __shfl_xor(cc, 2);
        cv += __shfl_xor(cv, 4);  cc += __shfl_xor(cc, 4);
        cv += __shfl_xor(cv, 8);  cc += __shfl_xor(cc, 8);
        if (t == 0) {
            atomicAdd(&accum[0], cv);
            atomicAdd(&accum[1], cc);
            __threadfence();
            int done = atomicAdd(counter, 1);
            if (done == 511) {   // last block finalizes
                float s = atomicAdd(&accum[0], 0.0f);
                float c = atomicAdd(&accum[1], 0.0f);
                outp[0] = s / fmaxf(c, 1.0f);
            }
        }
    }
}

extern "C" void kernel_launch(void* const* d_in, const int* in_sizes, int n_in,
                              void* d_out, int out_size, void* d_ws, size_t ws_size,
                              hipStream_t stream) {
    const float* feats_strong = (const float*)d_in[0];
    const float* feats_weak   = (const float*)d_in[1];
    const int*   s_lab        = (const int*)d_in[2];
    const int*   w_lab        = (const int*)d_in[3];
    const float* Wq           = (const float*)d_in[4];
    const float* bq           = (const float*)d_in[5];
    const float* Wk           = (const float*)d_in[6];
    const float* bk           = (const float*)d_in[7];
    const float* queue        = (const float*)d_in[8];

    float*    wsf = (float*)d_ws;
    int*      wsi = (int*)d_ws;

    float*    q_g   = wsf + OFF_Q;
    float*    k_g   = wsf + OFF_K;
    int*      table = wsi + OFF_TABLE;
    ushort_t* Wtq   = (ushort_t*)(wsi + OFF_WTQ);
    ushort_t* Wtk   = (ushort_t*)(wsi + OFF_WTK);
    int*      hist  = wsi + OFF_HIST;
    int*      rank  = wsi + OFF_RANK;
    int*      cnt   = wsi + OFF_CNT;
    int*      bhs   = wsi + OFF_BHS;
    int*      bhw   = wsi + OFF_BHW;
    float*    accum = wsf + OFF_ACC;
    ushort_t* Qt    = (ushort_t*)(wsi + OFF_QT);

    // K1: bf16 convert/transpose + label block-histograms + zero accum/counter
    cvtbh_k<<<448, 256, 0, stream>>>(Wq, Wk, queue, s_lab, w_lab,
                                     Wtq, Wtk, Qt, bhs, bhw, accum, cnt);
    // K2: both encoder GEMMs (reads Wt region before K3 clobbers it)
    enc_mfma_k<<<1024, 256, 0, stream>>>(feats_weak, feats_strong, Wtq, Wtk, bq, bk, q_g, k_g);
    // K3: rank + table + hist
    ranktab_k<<<64, 256, 0, stream>>>(s_lab, w_lab, bhs, bhw, table, rank, hist);
    // K4: idx + lpos + l_neg GEMM + CE + finalize
    ce_mfma_k<<<512, 256, 0, stream>>>(q_g, k_g, Qt, rank, table, w_lab, hist,
                                       accum, cnt, (float*)d_out);
}